// Round 3
// baseline (533.998 us; speedup 1.0000x reference)
//
#include <hip/hip_runtime.h>

#define D     4096   // row length
#define KKEEP 512    // entries to keep per row
#define TPB   512    // threads per block (one block per row), 8 waves
#define NSEG  2      // float4 segments per thread (D/4/TPB)
#define NB    2048   // histogram bins (11-bit digits; round 2 uses low 1024)
#define BPT   (NB / TPB)        // 4 bins per thread in the scan
#define SALT  4                 // lane-salted sub-counters per bin
#define HWORDS (NB * SALT)      // 8192 words = 32 KB
#define NWAVE (TPB / 64)        // 8

// Monotonic float -> uint key: preserves total order of floats as unsigned ints.
__device__ __forceinline__ unsigned key_of(float f) {
    unsigned u = __float_as_uint(f);
    return (u & 0x80000000u) ? ~u : (u | 0x80000000u);
}
// Exact inverse of key_of.
__device__ __forceinline__ float val_of(unsigned k) {
    unsigned u = (k & 0x80000000u) ? (k ^ 0x80000000u) : ~k;
    return __uint_as_float(u);
}

// (TPB,4): occupancy is LDS-limited to 4 blocks/CU (4x32KB=128KB<=160KB)
// either way; the 4 gives the allocator 128-VGPR headroom (no forced spills).
__global__ __launch_bounds__(TPB, 4)
void topk_keep_kernel(const float* __restrict__ x, float* __restrict__ out) {
    const int tid = threadIdx.x;
    const unsigned lane = tid & 63u, wid = (unsigned)tid >> 6;
    const unsigned salt = lane & (SALT - 1u);
    const float4* px = (const float4*)(x + (long)blockIdx.x * D);
    float4*       po = (float4*)(out + (long)blockIdx.x * D);

    // ---- Coalesced load: thread t owns float4 indices {t, t+512}.
    // Element index of (j, t, c) = j*2048 + 4t + c  → (j,t,c) lex == index order.
    unsigned k[NSEG * 4];
    {
        float4 f0 = px[tid], f1 = px[tid + TPB];
        k[0]=key_of(f0.x); k[1]=key_of(f0.y); k[2]=key_of(f0.z); k[3]=key_of(f0.w);
        k[4]=key_of(f1.x); k[5]=key_of(f1.y); k[6]=key_of(f1.z); k[7]=key_of(f1.w);
    }

    // hist layout: word = bin*4 + salt. Lanes colliding on one hot bin spread
    // across 4 addresses/banks (normal data has ~8.5% mass in the hottest
    // 11-bit digit -> same-address DS-atomic serialization was the bottleneck).
    // __align__(16): accessed via uint4* (ds_read_b128 needs 16B alignment).
    __shared__ __align__(16) unsigned hist[HWORDS];
    __shared__ unsigned s_wtot[NWAVE];  // per-wave chunk totals (select scan)
    __shared__ unsigned s_sel[2];       // [selected digit, new remaining]
    __shared__ unsigned s_p[NWAVE];     // tie phase: packed seg0|seg1 wave totals

    unsigned prefix = 0;   // decided high bits of threshold key (in place)
    unsigned rem = KKEEP;  // rank still to satisfy within current prefix subset

    // ---- 3-round radix select, fields [31:21], [20:10], [9:0] (MSB first)
    #pragma unroll
    for (int r = 0; r < 3; ++r) {
        const int shift = (r == 0) ? 21 : (r == 1) ? 10 : 0;
        const unsigned mask = (r == 2) ? 1023u : 2047u;

        // zero my 16-word chunk: 4x ds_write_b128, bank-tiled (64B per lane)
        {
            uint4 z = make_uint4(0u, 0u, 0u, 0u);
            uint4* hz = (uint4*)&hist[tid * (BPT * SALT)];
            hz[0] = z; hz[1] = z; hz[2] = z; hz[3] = z;
        }
        __syncthreads();

        if (r == 0) {
            #pragma unroll
            for (int j = 0; j < 8; ++j) {
                unsigned b = k[j] >> 21;
                atomicAdd(&hist[(b << 2) | salt], 1u);
            }
        } else {
            const int hs = (r == 1) ? 21 : 10;  // bits already decided
            #pragma unroll
            for (int j = 0; j < 8; ++j)
                if ((k[j] >> hs) == (prefix >> hs)) {
                    unsigned b = (k[j] >> shift) & mask;
                    atomicAdd(&hist[(b << 2) | salt], 1u);
                }
        }
        __syncthreads();

        // All-thread suffix scan: thread t owns bins [4t, 4t+4) = words [16t,16t+16)
        // (round 2 only populates bins < 1024; upper chunks read zeros -> ct=0)
        unsigned c[BPT];
        unsigned ct = 0;
        {
            const uint4* hb = (const uint4*)&hist[tid * (BPT * SALT)];
            #pragma unroll
            for (int i = 0; i < BPT; ++i) {
                uint4 w = hb[i];                  // ds_read_b128, bank-tiled
                c[i] = w.x + w.y + w.z + w.w;     // sum the 4 salts
                ct += c[i];
            }
        }
        unsigned s = ct;  // wave inclusive suffix scan of chunk totals
        #pragma unroll
        for (int off = 1; off < 64; off <<= 1) {
            unsigned t = __shfl_down(s, off, 64);
            if (lane + (unsigned)off < 64u) s += t;
        }
        if (lane == 0) s_wtot[wid] = s;
        __syncthreads();
        unsigned above = s - ct;
        #pragma unroll
        for (unsigned w = 0; w < NWAVE; ++w)
            if (w > wid) above += s_wtot[w];
        unsigned run = above;  // walk my 4 bins top-down; one bin crosses `rem`
        #pragma unroll
        for (int i = BPT - 1; i >= 0; --i) {
            unsigned incl = run + c[i];
            if (incl >= rem && run < rem) {
                s_sel[0] = (unsigned)(tid * BPT + i);
                s_sel[1] = rem - run;
            }
            run = incl;
        }
        __syncthreads();
        prefix |= s_sel[0] << shift;
        rem = s_sel[1];
    }

    const unsigned tkey = prefix;  // exact k-th largest key; rem = # equals to keep

    // ---- Tie-break rank in element-index order = (segment j, thread t, comp c).
    // Packed per-segment equal counts: p = e0 | e1<<16 (sums <= 4096 per half).
    unsigned e0 = (k[0]==tkey) + (k[1]==tkey) + (k[2]==tkey) + (k[3]==tkey);
    unsigned e1 = (k[4]==tkey) + (k[5]==tkey) + (k[6]==tkey) + (k[7]==tkey);
    unsigned p = e0 | (e1 << 16);
    unsigned ip = p;  // wave inclusive scan
    #pragma unroll
    for (int off = 1; off < 64; off <<= 1) {
        unsigned t = __shfl_up(ip, off, 64);
        if (lane >= (unsigned)off) ip += t;
    }
    if (lane == 63) s_p[wid] = ip;
    __syncthreads();
    unsigned xp = ip - p;  // exclusive within wave
    #pragma unroll
    for (unsigned w = 0; w < NWAVE; ++w)
        if (w < wid) xp += s_p[w];
    unsigned tot = 0;
    #pragma unroll
    for (unsigned w = 0; w < NWAVE; ++w) tot += s_p[w];
    const unsigned total0 = tot & 0xffffu;
    unsigned rank[NSEG];  // global equal-rank of my first equal in each segment
    rank[0] = xp & 0xffffu;
    rank[1] = total0 + (xp >> 16);

    // ---- Emit (coalesced): keep keys > tkey, plus equals with rank < rem
    #pragma unroll
    for (int j = 0; j < NSEG; ++j) {
        float4 o;
        unsigned eqr = rank[j];
        float* ofp = (float*)&o;
        #pragma unroll
        for (int c2 = 0; c2 < 4; ++c2) {
            unsigned kk = k[4*j + c2];
            bool keep;
            if (kk > tkey)       keep = true;
            else if (kk == tkey) { keep = (eqr < rem); ++eqr; }
            else                 keep = false;
            ofp[c2] = keep ? val_of(kk) : 0.0f;
        }
        po[tid + j * TPB] = o;
    }
}

extern "C" void kernel_launch(void* const* d_in, const int* in_sizes, int n_in,
                              void* d_out, int out_size, void* d_ws, size_t ws_size,
                              hipStream_t stream) {
    const float* x = (const float*)d_in[0];
    float* out = (float*)d_out;
    const int rows = in_sizes[0] / D;  // 4*4096 = 16384
    topk_keep_kernel<<<dim3(rows), dim3(TPB), 0, stream>>>(x, out);
}

// Round 4
// 439.838 us; speedup vs baseline: 1.2141x; 1.2141x over previous
//
#include <hip/hip_runtime.h>

#define D     4096   // row length
#define KKEEP 512    // entries to keep per row
#define TPB   256    // threads per block (one block per row)
#define NSEG  4      // float4 segments per thread (D/4/TPB)
#define NB    2048   // histogram bins (11-bit digits; round 2 uses low 1024 only)
#define BPT   (NB / TPB)             // 8 bins per thread in the scan
#define HA(d) ((d) + ((d) >> 3))     // padded hist address: chunk base = 9*tid
#define HWORDS (NB + NB / 8)         // 2304 words per salt copy
// 2-salt histogram: copy = lane&1. Second copy offset by HWORDS+1 words so
// same-bin/different-salt addresses land on DIFFERENT banks (2305 mod 32 = 1).
// Halves same-address DS-atomic serialization on hot bins (N(0,1): hottest
// 11-bit digit holds ~8.5% of elements -> ~5.4 colliding lanes/wave -> ~2.7).

// Monotonic float -> uint key: preserves total order of floats as unsigned ints.
__device__ __forceinline__ unsigned key_of(float f) {
    unsigned u = __float_as_uint(f);
    return (u & 0x80000000u) ? ~u : (u | 0x80000000u);
}
// Exact inverse of key_of.
__device__ __forceinline__ float val_of(unsigned k) {
    unsigned u = (k & 0x80000000u) ? (k ^ 0x80000000u) : ~k;
    return __uint_as_float(u);
}

__global__ __launch_bounds__(TPB, 8)
void topk_keep_kernel(const float* __restrict__ x, float* __restrict__ out) {
    const int tid = threadIdx.x;
    const unsigned lane = tid & 63u, wid = (unsigned)tid >> 6;
    const unsigned salt = lane & 1u;
    const float4* px = (const float4*)(x + (long)blockIdx.x * D);
    float4*       po = (float4*)(out + (long)blockIdx.x * D);

    // ---- Coalesced load: thread t owns float4 indices {t + 256*j}.
    // Element index of (j, t, c) = j*1024 + 4t + c  → (j,t,c) lex == index order.
    unsigned k[NSEG * 4];
    {
        float4 f0 = px[tid], f1 = px[tid + TPB], f2 = px[tid + 2 * TPB], f3 = px[tid + 3 * TPB];
        k[ 0]=key_of(f0.x); k[ 1]=key_of(f0.y); k[ 2]=key_of(f0.z); k[ 3]=key_of(f0.w);
        k[ 4]=key_of(f1.x); k[ 5]=key_of(f1.y); k[ 6]=key_of(f1.z); k[ 7]=key_of(f1.w);
        k[ 8]=key_of(f2.x); k[ 9]=key_of(f2.y); k[10]=key_of(f2.z); k[11]=key_of(f2.w);
        k[12]=key_of(f3.x); k[13]=key_of(f3.y); k[14]=key_of(f3.z); k[15]=key_of(f3.w);
    }

    __shared__ unsigned hist[2][HWORDS + 1];  // +1: bank-offset the salt copies
    __shared__ unsigned s_wtot[4];    // per-wave chunk totals (select scan)
    __shared__ unsigned s_sel[2];     // [selected digit, new remaining]
    __shared__ unsigned s_w01[4];     // tie phase: packed seg0|seg1 wave totals
    __shared__ unsigned s_w23[4];     // tie phase: packed seg2|seg3 wave totals

    unsigned prefix = 0;   // decided high bits of threshold key (in place)
    unsigned rem = KKEEP;  // rank still to satisfy within current prefix subset

    // ---- 3-round radix select, fields [31:21], [20:10], [9:0] (MSB first)
    #pragma unroll
    for (int r = 0; r < 3; ++r) {
        const int shift = (r == 0) ? 21 : (r == 1) ? 10 : 0;
        const unsigned mask = (r == 2) ? 1023u : 2047u;

        // zero both salt copies: stride-TPB b32, bank = tid mod 32 (conflict-free)
        #pragma unroll
        for (int i = 0; i < 9; ++i) {
            hist[0][tid + i * TPB] = 0;
            hist[1][tid + i * TPB] = 0;
        }
        __syncthreads();

        if (r == 0) {
            #pragma unroll
            for (int j = 0; j < 16; ++j)
                atomicAdd(&hist[salt][HA(k[j] >> 21)], 1u);
        } else {
            const int hs = (r == 1) ? 21 : 10;  // bits already decided
            #pragma unroll
            for (int j = 0; j < 16; ++j)
                if ((k[j] >> hs) == (prefix >> hs))
                    atomicAdd(&hist[salt][HA((k[j] >> shift) & mask)], 1u);
        }
        __syncthreads();

        // All-thread suffix scan: thread t owns bins [8t, 8t+8) at words 9t..9t+7
        // (9-stride: 9 coprime to 32 -> conflict-free b32 pattern)
        unsigned c[BPT];
        unsigned ct = 0;
        {
            const int hb = tid * 9;
            #pragma unroll
            for (int i = 0; i < BPT; ++i) {
                c[i] = hist[0][hb + i] + hist[1][hb + i];
                ct += c[i];
            }
        }
        unsigned s = ct;  // wave inclusive suffix scan of chunk totals
        #pragma unroll
        for (int off = 1; off < 64; off <<= 1) {
            unsigned t = __shfl_down(s, off, 64);
            if (lane + (unsigned)off < 64u) s += t;
        }
        if (lane == 0) s_wtot[wid] = s;
        __syncthreads();
        unsigned above = s - ct;
        #pragma unroll
        for (unsigned w = 0; w < 4; ++w)
            if (w > wid) above += s_wtot[w];
        unsigned run = above;  // walk my 8 bins top-down; one bin crosses `rem`
        #pragma unroll
        for (int i = BPT - 1; i >= 0; --i) {
            unsigned incl = run + c[i];
            if (incl >= rem && run < rem) {
                s_sel[0] = (unsigned)(tid * BPT + i);
                s_sel[1] = rem - run;
            }
            run = incl;
        }
        __syncthreads();
        prefix |= s_sel[0] << shift;
        rem = s_sel[1];
    }

    const unsigned tkey = prefix;  // exact k-th largest key; rem = # equals to keep

    // ---- Tie-break rank in element-index order = (segment j, thread t, comp c).
    // Packed per-segment equal counts: p01 = e0 | e1<<16, p23 = e2 | e3<<16.
    unsigned e[NSEG];
    #pragma unroll
    for (int j = 0; j < NSEG; ++j) {
        unsigned c0 = (k[4*j+0] == tkey), c1 = (k[4*j+1] == tkey);
        unsigned c2 = (k[4*j+2] == tkey), c3 = (k[4*j+3] == tkey);
        e[j] = c0 + c1 + c2 + c3;
    }
    unsigned p01 = e[0] | (e[1] << 16);
    unsigned p23 = e[2] | (e[3] << 16);
    unsigned i01 = p01, i23 = p23;  // wave inclusive scans (sums ≤1024 per half)
    #pragma unroll
    for (int off = 1; off < 64; off <<= 1) {
        unsigned t0 = __shfl_up(i01, off, 64);
        unsigned t1 = __shfl_up(i23, off, 64);
        if (lane >= (unsigned)off) { i01 += t0; i23 += t1; }
    }
    if (lane == 63) { s_w01[wid] = i01; s_w23[wid] = i23; }
    __syncthreads();
    unsigned x01 = i01 - p01, x23 = i23 - p23;  // exclusive within wave
    #pragma unroll
    for (unsigned w = 0; w < 4; ++w)
        if (w < wid) { x01 += s_w01[w]; x23 += s_w23[w]; }
    const unsigned tot01 = s_w01[0] + s_w01[1] + s_w01[2] + s_w01[3];
    const unsigned tot23 = s_w23[0] + s_w23[1] + s_w23[2] + s_w23[3];
    const unsigned total0 = tot01 & 0xffffu, total1 = tot01 >> 16;
    const unsigned total2 = tot23 & 0xffffu;
    unsigned rank[NSEG];  // global equal-rank of my first equal in each segment
    rank[0] = (x01 & 0xffffu);
    rank[1] = total0 + (x01 >> 16);
    rank[2] = total0 + total1 + (x23 & 0xffffu);
    rank[3] = total0 + total1 + total2 + (x23 >> 16);

    // ---- Emit (coalesced): keep keys > tkey, plus equals with rank < rem
    #pragma unroll
    for (int j = 0; j < NSEG; ++j) {
        float4 o;
        unsigned eqr = rank[j];
        float* ofp = (float*)&o;
        #pragma unroll
        for (int c = 0; c < 4; ++c) {
            unsigned kk = k[4*j + c];
            bool keep;
            if (kk > tkey)       keep = true;
            else if (kk == tkey) { keep = (eqr < rem); ++eqr; }
            else                 keep = false;
            ofp[c] = keep ? val_of(kk) : 0.0f;
        }
        po[tid + j * TPB] = o;
    }
}

extern "C" void kernel_launch(void* const* d_in, const int* in_sizes, int n_in,
                              void* d_out, int out_size, void* d_ws, size_t ws_size,
                              hipStream_t stream) {
    const float* x = (const float*)d_in[0];
    float* out = (float*)d_out;
    const int rows = in_sizes[0] / D;  // 4*4096 = 16384
    topk_keep_kernel<<<dim3(rows), dim3(TPB), 0, stream>>>(x, out);
}

// Round 5
// 431.462 us; speedup vs baseline: 1.2377x; 1.0194x over previous
//
#include <hip/hip_runtime.h>

#define D     4096   // row length
#define KKEEP 512    // entries to keep per row
#define TPB   256    // threads per block (one block per row)
#define NSEG  4      // float4 segments per thread (D/4/TPB)
#define NB    2048   // histogram bins (11-bit digits; round 2 uses low 1024 only)
#define BPT   (NB / TPB)             // 8 bins per thread in the scan
#define HA(d) ((d) + ((d) >> 3))     // padded hist address: chunk base = 9*tid
#define HWORDS (NB + NB / 8)         // 2304 words

// Monotonic float -> uint key: preserves total order of floats as unsigned ints.
__device__ __forceinline__ unsigned key_of(float f) {
    unsigned u = __float_as_uint(f);
    return (u & 0x80000000u) ? ~u : (u | 0x80000000u);
}
// Exact inverse of key_of.
__device__ __forceinline__ float val_of(unsigned k) {
    unsigned u = (k & 0x80000000u) ? (k ^ 0x80000000u) : ~k;
    return __uint_as_float(u);
}

__global__ __launch_bounds__(TPB, 8)
void topk_keep_kernel(const float* __restrict__ x, float* __restrict__ out) {
    const int tid = threadIdx.x;
    const unsigned lane = tid & 63u, wid = (unsigned)tid >> 6;
    const float4* px = (const float4*)(x + (long)blockIdx.x * D);
    float4*       po = (float4*)(out + (long)blockIdx.x * D);

    // ---- Coalesced load: thread t owns float4 indices {t + 256*j}.
    // Element index of (j, t, c) = j*1024 + 4t + c  → (j,t,c) lex == index order.
    unsigned k[NSEG * 4];
    {
        float4 f0 = px[tid], f1 = px[tid + TPB], f2 = px[tid + 2 * TPB], f3 = px[tid + 3 * TPB];
        k[ 0]=key_of(f0.x); k[ 1]=key_of(f0.y); k[ 2]=key_of(f0.z); k[ 3]=key_of(f0.w);
        k[ 4]=key_of(f1.x); k[ 5]=key_of(f1.y); k[ 6]=key_of(f1.z); k[ 7]=key_of(f1.w);
        k[ 8]=key_of(f2.x); k[ 9]=key_of(f2.y); k[10]=key_of(f2.z); k[11]=key_of(f2.w);
        k[12]=key_of(f3.x); k[13]=key_of(f3.y); k[14]=key_of(f3.z); k[15]=key_of(f3.w);
    }

    __shared__ unsigned hist[HWORDS];
    __shared__ unsigned s_wtot[4];    // per-wave chunk totals (select scan)
    __shared__ unsigned s_sel[2];     // [selected digit, new remaining]
    __shared__ unsigned s_w01[4];     // tie phase: packed seg0|seg1 wave totals
    __shared__ unsigned s_w23[4];     // tie phase: packed seg2|seg3 wave totals

    // Zero ONCE up front (incl. pad words 9t+8, never touched by atomics).
    // Rounds 0/1 re-zero their bins during the scan read-out (read-then-zero,
    // same conflict-free 9-stride), so no per-round zero pass or its barrier.
    #pragma unroll
    for (int i = 0; i < 9; ++i) hist[tid + i * TPB] = 0;
    __syncthreads();

    unsigned prefix = 0;   // decided high bits of threshold key (in place)
    unsigned rem = KKEEP;  // rank still to satisfy within current prefix subset

    // ---- 3-round radix select, fields [31:21], [20:10], [9:0] (MSB first)
    #pragma unroll
    for (int r = 0; r < 3; ++r) {
        const int shift = (r == 0) ? 21 : (r == 1) ? 10 : 0;
        const unsigned mask = (r == 2) ? 1023u : 2047u;

        if (r == 0) {
            #pragma unroll
            for (int j = 0; j < 16; ++j)
                atomicAdd(&hist[HA(k[j] >> 21)], 1u);
        } else {
            const int hs = (r == 1) ? 21 : 10;  // bits already decided
            #pragma unroll
            for (int j = 0; j < 16; ++j)
                if ((k[j] >> hs) == (prefix >> hs))
                    atomicAdd(&hist[HA((k[j] >> shift) & mask)], 1u);
        }
        __syncthreads();

        // All-thread suffix scan: thread t owns bins [8t, 8t+8) at words 9t..9t+7
        // (9 coprime to 32 -> conflict-free). Fused re-zero for the next round.
        unsigned c[BPT];
        unsigned ct = 0;
        {
            const int hb = tid * 9;
            #pragma unroll
            for (int i = 0; i < BPT; ++i) { c[i] = hist[hb + i]; ct += c[i]; }
            if (r < 2) {
                #pragma unroll
                for (int i = 0; i < BPT; ++i) hist[hb + i] = 0;
            }
        }
        unsigned s = ct;  // wave inclusive suffix scan of chunk totals
        #pragma unroll
        for (int off = 1; off < 64; off <<= 1) {
            unsigned t = __shfl_down(s, off, 64);
            if (lane + (unsigned)off < 64u) s += t;
        }
        if (lane == 0) s_wtot[wid] = s;
        __syncthreads();
        unsigned above = s - ct;
        #pragma unroll
        for (unsigned w = 0; w < 4; ++w)
            if (w > wid) above += s_wtot[w];
        unsigned run = above;  // walk my 8 bins top-down; one bin crosses `rem`
        #pragma unroll
        for (int i = BPT - 1; i >= 0; --i) {
            unsigned incl = run + c[i];
            if (incl >= rem && run < rem) {
                s_sel[0] = (unsigned)(tid * BPT + i);
                s_sel[1] = rem - run;
            }
            run = incl;
        }
        __syncthreads();
        prefix |= s_sel[0] << shift;
        rem = s_sel[1];
    }

    const unsigned tkey = prefix;  // exact k-th largest key; rem = # equals to keep

    // ---- Tie-break rank in element-index order = (segment j, thread t, comp c).
    // Packed per-segment equal counts: p01 = e0 | e1<<16, p23 = e2 | e3<<16.
    unsigned e[NSEG];
    #pragma unroll
    for (int j = 0; j < NSEG; ++j) {
        unsigned c0 = (k[4*j+0] == tkey), c1 = (k[4*j+1] == tkey);
        unsigned c2 = (k[4*j+2] == tkey), c3 = (k[4*j+3] == tkey);
        e[j] = c0 + c1 + c2 + c3;
    }
    unsigned p01 = e[0] | (e[1] << 16);
    unsigned p23 = e[2] | (e[3] << 16);
    unsigned i01 = p01, i23 = p23;  // wave inclusive scans (sums ≤1024 per half)
    #pragma unroll
    for (int off = 1; off < 64; off <<= 1) {
        unsigned t0 = __shfl_up(i01, off, 64);
        unsigned t1 = __shfl_up(i23, off, 64);
        if (lane >= (unsigned)off) { i01 += t0; i23 += t1; }
    }
    if (lane == 63) { s_w01[wid] = i01; s_w23[wid] = i23; }
    __syncthreads();
    unsigned x01 = i01 - p01, x23 = i23 - p23;  // exclusive within wave
    #pragma unroll
    for (unsigned w = 0; w < 4; ++w)
        if (w < wid) { x01 += s_w01[w]; x23 += s_w23[w]; }
    const unsigned tot01 = s_w01[0] + s_w01[1] + s_w01[2] + s_w01[3];
    const unsigned tot23 = s_w23[0] + s_w23[1] + s_w23[2] + s_w23[3];
    const unsigned total0 = tot01 & 0xffffu, total1 = tot01 >> 16;
    const unsigned total2 = tot23 & 0xffffu;
    unsigned rank[NSEG];  // global equal-rank of my first equal in each segment
    rank[0] = (x01 & 0xffffu);
    rank[1] = total0 + (x01 >> 16);
    rank[2] = total0 + total1 + (x23 & 0xffffu);
    rank[3] = total0 + total1 + total2 + (x23 >> 16);

    // ---- Emit (coalesced): keep keys > tkey, plus equals with rank < rem
    #pragma unroll
    for (int j = 0; j < NSEG; ++j) {
        float4 o;
        unsigned eqr = rank[j];
        float* ofp = (float*)&o;
        #pragma unroll
        for (int c = 0; c < 4; ++c) {
            unsigned kk = k[4*j + c];
            bool keep;
            if (kk > tkey)       keep = true;
            else if (kk == tkey) { keep = (eqr < rem); ++eqr; }
            else                 keep = false;
            ofp[c] = keep ? val_of(kk) : 0.0f;
        }
        po[tid + j * TPB] = o;
    }
}

extern "C" void kernel_launch(void* const* d_in, const int* in_sizes, int n_in,
                              void* d_out, int out_size, void* d_ws, size_t ws_size,
                              hipStream_t stream) {
    const float* x = (const float*)d_in[0];
    float* out = (float*)d_out;
    const int rows = in_sizes[0] / D;  // 4*4096 = 16384
    topk_keep_kernel<<<dim3(rows), dim3(TPB), 0, stream>>>(x, out);
}